// Round 1
// baseline (362.643 us; speedup 1.0000x reference)
//
#include <hip/hip_runtime.h>
#include <hip/hip_bf16.h>

#define DEVINL __device__ __forceinline__

typedef short bf16x8 __attribute__((ext_vector_type(8)));
typedef float f32x4  __attribute__((ext_vector_type(4)));

struct alignas(8) S4 { short x, y, z, w; };

DEVINL short f2bf(float f) {
  __hip_bfloat16 h = __float2bfloat16(f);
  short s; __builtin_memcpy(&s, &h, 2); return s;
}

DEVINL f32x4 mfma16(bf16x8 a, bf16x8 b, f32x4 c) {
  return __builtin_amdgcn_mfma_f32_16x16x32_bf16(a, b, c, 0, 0, 0);
}

#define CC 256
#define C4 64
#define BB 2
#define NQ 8192
#define NK 8192

// ---------------- setup: weights -> bf16, BN folded into scale/bias ----------
__global__ void k_setup(const float* __restrict__ wq, const float* __restrict__ wk,
                        const float* __restrict__ wv, const float* __restrict__ wt,
                        const float* __restrict__ bt, const float* __restrict__ gmm,
                        const float* __restrict__ bet, const float* __restrict__ rmean,
                        const float* __restrict__ rvar,
                        short* __restrict__ wqb, short* __restrict__ wkb,
                        short* __restrict__ wvb, short* __restrict__ wtb,
                        float* __restrict__ scale, float* __restrict__ bias) {
  int i = blockIdx.x * 256 + threadIdx.x;
  if (i < C4 * CC) { wqb[i] = f2bf(wq[i]); wkb[i] = f2bf(wk[i]); }
  if (i < CC * CC) { wvb[i] = f2bf(wv[i]); wtb[i] = f2bf(wt[i]); }
  if (i < CC) {
    float s = gmm[i] * rsqrtf(rvar[i] + 1e-5f);
    scale[i] = s;
    bias[i]  = (bt[i] - rmean[i]) * s + bet[i];
  }
}

// ---------------- proj q/k: out[M,64] bf16 row-major -------------------------
__global__ __launch_bounds__(256)
void k_projqk(const float* __restrict__ q, const float* __restrict__ kv,
              const short* __restrict__ wqb, const short* __restrict__ wkb,
              short* __restrict__ xq, short* __restrict__ xk) {
  const float* A; const short* W; short* O;
  if (blockIdx.y == 0) { A = q; W = wqb; O = xq; } else { A = kv; W = wkb; O = xk; }
  const int lane = threadIdx.x & 63, w = threadIdx.x >> 6;
  const int rowbase = blockIdx.x * 128 + w * 32;
  const int lr = lane & 15, lg = lane >> 4;
  f32x4 acc[2][4] = {};
#pragma unroll
  for (int kf = 0; kf < 8; ++kf) {
    bf16x8 a[2];
#pragma unroll
    for (int mf = 0; mf < 2; ++mf) {
      const float* p = A + (size_t)(rowbase + mf * 16 + lr) * CC + kf * 32 + lg * 8;
      float4 x0 = *(const float4*)p, x1 = *(const float4*)(p + 4);
      bf16x8 t;
      t[0] = f2bf(x0.x); t[1] = f2bf(x0.y); t[2] = f2bf(x0.z); t[3] = f2bf(x0.w);
      t[4] = f2bf(x1.x); t[5] = f2bf(x1.y); t[6] = f2bf(x1.z); t[7] = f2bf(x1.w);
      a[mf] = t;
    }
#pragma unroll
    for (int nf = 0; nf < 4; ++nf) {
      bf16x8 b = *(const bf16x8*)(W + (size_t)(nf * 16 + lr) * CC + kf * 32 + lg * 8);
      acc[0][nf] = mfma16(a[0], b, acc[0][nf]);
      acc[1][nf] = mfma16(a[1], b, acc[1][nf]);
    }
  }
#pragma unroll
  for (int mf = 0; mf < 2; ++mf)
#pragma unroll
    for (int nf = 0; nf < 4; ++nf)
#pragma unroll
      for (int r = 0; r < 4; ++r)
        O[(size_t)(rowbase + mf * 16 + lg * 4 + r) * C4 + nf * 16 + lr] = f2bf(acc[mf][nf][r]);
}

// ---------------- proj v: out vt[b][tile][c][key] bf16 (per-64-key transposed)
__global__ __launch_bounds__(256)
void k_projv(const float* __restrict__ kv, const short* __restrict__ wvb,
             short* __restrict__ vt) {
  const int lane = threadIdx.x & 63, w = threadIdx.x >> 6;
  const int rowbase = blockIdx.x * 128 + w * 32;
  const int cb = blockIdx.y * 128;
  const int lr = lane & 15, lg = lane >> 4;
  f32x4 acc[2][8] = {};
#pragma unroll
  for (int kf = 0; kf < 8; ++kf) {
    bf16x8 a[2];
#pragma unroll
    for (int mf = 0; mf < 2; ++mf) {
      const float* p = kv + (size_t)(rowbase + mf * 16 + lr) * CC + kf * 32 + lg * 8;
      float4 x0 = *(const float4*)p, x1 = *(const float4*)(p + 4);
      bf16x8 t;
      t[0] = f2bf(x0.x); t[1] = f2bf(x0.y); t[2] = f2bf(x0.z); t[3] = f2bf(x0.w);
      t[4] = f2bf(x1.x); t[5] = f2bf(x1.y); t[6] = f2bf(x1.z); t[7] = f2bf(x1.w);
      a[mf] = t;
    }
#pragma unroll
    for (int nf = 0; nf < 8; ++nf) {
      bf16x8 b = *(const bf16x8*)(wvb + (size_t)(cb + nf * 16 + lr) * CC + kf * 32 + lg * 8);
      acc[0][nf] = mfma16(a[0], b, acc[0][nf]);
      acc[1][nf] = mfma16(a[1], b, acc[1][nf]);
    }
  }
#pragma unroll
  for (int mf = 0; mf < 2; ++mf) {
    int row = rowbase + mf * 16 + lg * 4;     // 4 consecutive rows, same 64-tile
    int bidx = row >> 13, kib = row & 8191;
    int tile = kib >> 6, kk = kib & 63;
#pragma unroll
    for (int nf = 0; nf < 8; ++nf) {
      int c = cb + nf * 16 + lr;
      S4 st;
      st.x = f2bf(acc[mf][nf][0]); st.y = f2bf(acc[mf][nf][1]);
      st.z = f2bf(acc[mf][nf][2]); st.w = f2bf(acc[mf][nf][3]);
      *(S4*)(vt + (((size_t)bidx * 128 + tile) * CC + c) * 64 + kk) = st;
    }
  }
}

// ---------------- flash attention: xr = softmax(xq xk^T) vt ------------------
__global__ __launch_bounds__(256)
void k_attn(const short* __restrict__ xq, const short* __restrict__ xk,
            const short* __restrict__ vt, float* __restrict__ xr) {
  __shared__ char Kt[8192];     // [64 key][64 d] bf16, chunk-swizzled
  __shared__ char Vt[32768];    // [256 c][64 key] bf16, chunk-swizzled
  __shared__ char Pb[8192];     // per-wave [16 q][64 key] bf16, chunk-swizzled
  const int tid = threadIdx.x;
  const int lane = tid & 63, w = tid >> 6;
  const int lr = lane & 15, lg = lane >> 4;
  const int b = blockIdx.y, qt = blockIdx.x;

  bf16x8 qa[2];
  {
    const short* qrow = xq + (size_t)(b * NQ + qt * 64 + w * 16 + lr) * C4;
    qa[0] = *(const bf16x8*)(qrow + lg * 8);
    qa[1] = *(const bf16x8*)(qrow + 32 + lg * 8);
  }
  f32x4 o[16] = {};
  float m[4] = {-1e30f, -1e30f, -1e30f, -1e30f};
  float l[4] = {};
  char* pb = Pb + w * 2048;
  const short* kbase = xk + (size_t)b * NK * C4;
  const short* vbase = vt + (size_t)b * 128 * 16384;

#pragma unroll 1
  for (int kt = 0; kt < NK / 64; ++kt) {
    // ---- stage K tile (8KB) and V^T tile (32KB), XOR chunk swizzle
    {
      const short* ks = kbase + kt * 64 * C4;
#pragma unroll
      for (int j = 0; j < 2; ++j) {
        int id = j * 256 + tid, row = id >> 3, c = id & 7;
        uint4 d = *(const uint4*)(ks + row * 64 + c * 8);
        *(uint4*)(Kt + row * 128 + ((c ^ (row & 7)) << 4)) = d;
      }
      const short* vs = vbase + kt * 16384;
#pragma unroll
      for (int j = 0; j < 8; ++j) {
        int id = j * 256 + tid, row = id >> 3, c = id & 7;
        uint4 d = *(const uint4*)(vs + id * 8);
        *(uint4*)(Vt + row * 128 + ((c ^ (row & 7)) << 4)) = d;
      }
    }
    __syncthreads();
    // ---- S = Q K^T (16 q-rows per wave x 64 keys)
    f32x4 s[4] = {};
#pragma unroll
    for (int nf = 0; nf < 4; ++nf) {
      int key = nf * 16 + lr;
#pragma unroll
      for (int kf = 0; kf < 2; ++kf) {
        int ch = kf * 4 + lg;
        bf16x8 kb2 = *(const bf16x8*)(Kt + key * 128 + ((ch ^ (key & 7)) << 4));
        s[nf] = mfma16(qa[kf], kb2, s[nf]);
      }
    }
    // ---- online softmax (rows q = lg*4 + r live in lanes sharing lg)
    float tmax[4], alpha[4], rsum[4];
#pragma unroll
    for (int r = 0; r < 4; ++r)
      tmax[r] = fmaxf(fmaxf(s[0][r], s[1][r]), fmaxf(s[2][r], s[3][r]));
#pragma unroll
    for (int msk = 1; msk <= 8; msk <<= 1)
#pragma unroll
      for (int r = 0; r < 4; ++r)
        tmax[r] = fmaxf(tmax[r], __shfl_xor(tmax[r], msk));
#pragma unroll
    for (int r = 0; r < 4; ++r) {
      float mn = fmaxf(m[r], tmax[r]);
      alpha[r] = __expf(m[r] - mn);
      m[r] = mn;
      rsum[r] = 0.f;
    }
#pragma unroll
    for (int nf = 0; nf < 4; ++nf)
#pragma unroll
      for (int r = 0; r < 4; ++r) {
        float p = __expf(s[nf][r] - m[r]);
        s[nf][r] = p;
        rsum[r] += p;
      }
#pragma unroll
    for (int msk = 1; msk <= 8; msk <<= 1)
#pragma unroll
      for (int r = 0; r < 4; ++r)
        rsum[r] += __shfl_xor(rsum[r], msk);
#pragma unroll
    for (int r = 0; r < 4; ++r)
      l[r] = l[r] * alpha[r] + rsum[r];
#pragma unroll
    for (int cf = 0; cf < 16; ++cf) {
      f32x4 t = o[cf];
      t[0] *= alpha[0]; t[1] *= alpha[1]; t[2] *= alpha[2]; t[3] *= alpha[3];
      o[cf] = t;
    }
    // ---- P (D-frag layout) -> per-wave LDS, re-read as A-frag
#pragma unroll
    for (int nf = 0; nf < 4; ++nf)
#pragma unroll
      for (int r = 0; r < 4; ++r) {
        int qq = lg * 4 + r, key = nf * 16 + lr;
        *(short*)(pb + qq * 128 + (((key >> 3) ^ (qq & 7)) << 4) + (key & 7) * 2) =
            f2bf(s[nf][r]);
      }
    asm volatile("s_waitcnt lgkmcnt(0)" ::: "memory");
    bf16x8 pa[2];
#pragma unroll
    for (int kf = 0; kf < 2; ++kf) {
      int ch = kf * 4 + lg;
      pa[kf] = *(const bf16x8*)(pb + lr * 128 + ((ch ^ (lr & 7)) << 4));
    }
    // ---- O += P V
#pragma unroll
    for (int cf = 0; cf < 16; ++cf) {
      int c = cf * 16 + lr;
#pragma unroll
      for (int kf = 0; kf < 2; ++kf) {
        int ch = kf * 4 + lg;
        bf16x8 vb = *(const bf16x8*)(Vt + c * 128 + ((ch ^ (c & 7)) << 4));
        o[cf] = mfma16(pa[kf], vb, o[cf]);
      }
    }
    __syncthreads();
  }
  // ---- normalize + write x_r (fp32)
  float inv[4];
#pragma unroll
  for (int r = 0; r < 4; ++r) inv[r] = 1.f / l[r];
#pragma unroll
  for (int cf = 0; cf < 16; ++cf)
#pragma unroll
    for (int r = 0; r < 4; ++r) {
      int row = qt * 64 + w * 16 + lg * 4 + r;
      xr[((size_t)b * NQ + row) * CC + cf * 16 + lr] = o[cf][r] * inv[r];
    }
}

// ---------------- epilogue: out = relu(BN((q - xr) wt^T + bt)) + q -----------
__global__ __launch_bounds__(256)
void k_epilogue(const float* __restrict__ q, const float* __restrict__ xr,
                const short* __restrict__ wtb, const float* __restrict__ scale,
                const float* __restrict__ bias, float* __restrict__ out) {
  const int lane = threadIdx.x & 63, w = threadIdx.x >> 6;
  const int rowbase = blockIdx.x * 128 + w * 32;
  const int cb = blockIdx.y * 128;
  const int lr = lane & 15, lg = lane >> 4;
  f32x4 acc[2][8] = {};
#pragma unroll
  for (int kf = 0; kf < 8; ++kf) {
    bf16x8 a[2];
#pragma unroll
    for (int mf = 0; mf < 2; ++mf) {
      size_t base = (size_t)(rowbase + mf * 16 + lr) * CC + kf * 32 + lg * 8;
      float4 q0 = *(const float4*)(q + base), q1 = *(const float4*)(q + base + 4);
      float4 r0 = *(const float4*)(xr + base), r1 = *(const float4*)(xr + base + 4);
      bf16x8 t;
      t[0] = f2bf(q0.x - r0.x); t[1] = f2bf(q0.y - r0.y);
      t[2] = f2bf(q0.z - r0.z); t[3] = f2bf(q0.w - r0.w);
      t[4] = f2bf(q1.x - r1.x); t[5] = f2bf(q1.y - r1.y);
      t[6] = f2bf(q1.z - r1.z); t[7] = f2bf(q1.w - r1.w);
      a[mf] = t;
    }
#pragma unroll
    for (int nf = 0; nf < 8; ++nf) {
      bf16x8 b = *(const bf16x8*)(wtb + (size_t)(cb + nf * 16 + lr) * CC + kf * 32 + lg * 8);
      acc[0][nf] = mfma16(a[0], b, acc[0][nf]);
      acc[1][nf] = mfma16(a[1], b, acc[1][nf]);
    }
  }
#pragma unroll
  for (int nf = 0; nf < 8; ++nf) {
    int c = cb + nf * 16 + lr;
    float sc = scale[c], bi = bias[c];
#pragma unroll
    for (int mf = 0; mf < 2; ++mf)
#pragma unroll
      for (int r = 0; r < 4; ++r) {
        int row = rowbase + mf * 16 + lg * 4 + r;
        float y = acc[mf][nf][r] * sc + bi;
        y = fmaxf(y, 0.f) + q[(size_t)row * CC + c];
        out[(size_t)row * CC + c] = y;
      }
  }
}

// ---------------- launch -----------------------------------------------------
extern "C" void kernel_launch(void* const* d_in, const int* in_sizes, int n_in,
                              void* d_out, int out_size, void* d_ws, size_t ws_size,
                              hipStream_t stream) {
  const float* q     = (const float*)d_in[0];
  const float* kv    = (const float*)d_in[1];
  const float* wq    = (const float*)d_in[2];
  const float* wk    = (const float*)d_in[3];
  const float* wv    = (const float*)d_in[4];
  const float* wt    = (const float*)d_in[5];
  const float* bt    = (const float*)d_in[6];
  const float* gmm   = (const float*)d_in[7];
  const float* bet   = (const float*)d_in[8];
  const float* rmean = (const float*)d_in[9];
  const float* rvar  = (const float*)d_in[10];
  float* out = (float*)d_out;
  char* ws = (char*)d_ws;

  short* wqb  = (short*)(ws + 0);         // 32 KB
  short* wkb  = (short*)(ws + 32768);     // 32 KB
  short* wvb  = (short*)(ws + 65536);     // 128 KB
  short* wtb  = (short*)(ws + 196608);    // 128 KB
  float* scale= (float*)(ws + 327680);    // 1 KB
  float* bias = (float*)(ws + 328704);    // 1 KB
  short* xq   = (short*)(ws + 329728);    // 2 MB
  short* xk   = (short*)(ws + 2426880);   // 2 MB
  short* vt   = (short*)(ws + 4524032);   // 8 MB
  float* xr   = (float*)(ws + 12912640);  // 16 MB  (total ~29.7 MB)

  k_setup<<<256, 256, 0, stream>>>(wq, wk, wv, wt, bt, gmm, bet, rmean, rvar,
                                   wqb, wkb, wvb, wtb, scale, bias);
  k_projqk<<<dim3(128, 2), 256, 0, stream>>>(q, kv, wqb, wkb, xq, xk);
  k_projv<<<dim3(128, 2), 256, 0, stream>>>(kv, wvb, vt);
  k_attn<<<dim3(128, 2), 256, 0, stream>>>(xq, xk, vt, xr);
  k_epilogue<<<dim3(128, 2), 256, 0, stream>>>(q, xr, wtb, scale, bias, out);
}

// Round 2
// 264.725 us; speedup vs baseline: 1.3699x; 1.3699x over previous
//
#include <hip/hip_runtime.h>
#include <hip/hip_bf16.h>

#define DEVINL __device__ __forceinline__

typedef short bf16x8 __attribute__((ext_vector_type(8)));
typedef float f32x4  __attribute__((ext_vector_type(4)));

struct alignas(8) S4 { short x, y, z, w; };

DEVINL short f2bf(float f) {
  __hip_bfloat16 h = __float2bfloat16(f);
  short s; __builtin_memcpy(&s, &h, 2); return s;
}
DEVINL float bf2f(short s) {
  unsigned u = ((unsigned)(unsigned short)s) << 16;
  float f; __builtin_memcpy(&f, &u, 4); return f;
}

DEVINL f32x4 mfma16(bf16x8 a, bf16x8 b, f32x4 c) {
  return __builtin_amdgcn_mfma_f32_16x16x32_bf16(a, b, c, 0, 0, 0);
}

#define CC 256
#define C4 64
#define BB 2
#define NQ 8192
#define NK 8192
#define NROWS (BB * NQ)

// ---------------- setup: weights -> bf16, BN folded into scale/bias ----------
__global__ void k_setup(const float* __restrict__ wq, const float* __restrict__ wk,
                        const float* __restrict__ wv, const float* __restrict__ wt,
                        const float* __restrict__ bt, const float* __restrict__ gmm,
                        const float* __restrict__ bet, const float* __restrict__ rmean,
                        const float* __restrict__ rvar,
                        short* __restrict__ wqb, short* __restrict__ wkb,
                        short* __restrict__ wvb, short* __restrict__ wtb,
                        float* __restrict__ scale, float* __restrict__ bias) {
  int i = blockIdx.x * 256 + threadIdx.x;
  if (i < C4 * CC) { wqb[i] = f2bf(wq[i]); wkb[i] = f2bf(wk[i]); }
  if (i < CC * CC) { wvb[i] = f2bf(wv[i]); wtb[i] = f2bf(wt[i]); }
  if (i < CC) {
    float s = gmm[i] * rsqrtf(rvar[i] + 1e-5f);
    scale[i] = s;
    bias[i]  = (bt[i] - rmean[i]) * s + bet[i];
  }
}

// ---------------- proj q/k: out[M,64] bf16 row-major -------------------------
__global__ __launch_bounds__(256)
void k_projqk(const float* __restrict__ q, const float* __restrict__ kv,
              const short* __restrict__ wqb, const short* __restrict__ wkb,
              short* __restrict__ xq, short* __restrict__ xk) {
  const float* A; const short* W; short* O;
  if (blockIdx.y == 0) { A = q; W = wqb; O = xq; } else { A = kv; W = wkb; O = xk; }
  const int lane = threadIdx.x & 63, w = threadIdx.x >> 6;
  const int rowbase = blockIdx.x * 128 + w * 32;
  const int lr = lane & 15, lg = lane >> 4;
  f32x4 acc[2][4] = {};
#pragma unroll
  for (int kf = 0; kf < 8; ++kf) {
    bf16x8 a[2];
#pragma unroll
    for (int mf = 0; mf < 2; ++mf) {
      const float* p = A + (size_t)(rowbase + mf * 16 + lr) * CC + kf * 32 + lg * 8;
      float4 x0 = *(const float4*)p, x1 = *(const float4*)(p + 4);
      bf16x8 t;
      t[0] = f2bf(x0.x); t[1] = f2bf(x0.y); t[2] = f2bf(x0.z); t[3] = f2bf(x0.w);
      t[4] = f2bf(x1.x); t[5] = f2bf(x1.y); t[6] = f2bf(x1.z); t[7] = f2bf(x1.w);
      a[mf] = t;
    }
#pragma unroll
    for (int nf = 0; nf < 4; ++nf) {
      bf16x8 b = *(const bf16x8*)(W + (size_t)(nf * 16 + lr) * CC + kf * 32 + lg * 8);
      acc[0][nf] = mfma16(a[0], b, acc[0][nf]);
      acc[1][nf] = mfma16(a[1], b, acc[1][nf]);
    }
  }
#pragma unroll
  for (int mf = 0; mf < 2; ++mf)
#pragma unroll
    for (int nf = 0; nf < 4; ++nf)
#pragma unroll
      for (int r = 0; r < 4; ++r)
        O[(size_t)(rowbase + mf * 16 + lg * 4 + r) * C4 + nf * 16 + lr] = f2bf(acc[mf][nf][r]);
}

// ---------------- proj v: out vt[b][tile][c][key] bf16 (per-64-key transposed)
__global__ __launch_bounds__(256)
void k_projv(const float* __restrict__ kv, const short* __restrict__ wvb,
             short* __restrict__ vt) {
  const int lane = threadIdx.x & 63, w = threadIdx.x >> 6;
  const int rowbase = blockIdx.x * 128 + w * 32;
  const int cb = blockIdx.y * 128;
  const int lr = lane & 15, lg = lane >> 4;
  f32x4 acc[2][8] = {};
#pragma unroll
  for (int kf = 0; kf < 8; ++kf) {
    bf16x8 a[2];
#pragma unroll
    for (int mf = 0; mf < 2; ++mf) {
      const float* p = kv + (size_t)(rowbase + mf * 16 + lr) * CC + kf * 32 + lg * 8;
      float4 x0 = *(const float4*)p, x1 = *(const float4*)(p + 4);
      bf16x8 t;
      t[0] = f2bf(x0.x); t[1] = f2bf(x0.y); t[2] = f2bf(x0.z); t[3] = f2bf(x0.w);
      t[4] = f2bf(x1.x); t[5] = f2bf(x1.y); t[6] = f2bf(x1.z); t[7] = f2bf(x1.w);
      a[mf] = t;
    }
#pragma unroll
    for (int nf = 0; nf < 8; ++nf) {
      bf16x8 b = *(const bf16x8*)(wvb + (size_t)(cb + nf * 16 + lr) * CC + kf * 32 + lg * 8);
      acc[0][nf] = mfma16(a[0], b, acc[0][nf]);
      acc[1][nf] = mfma16(a[1], b, acc[1][nf]);
    }
  }
#pragma unroll
  for (int mf = 0; mf < 2; ++mf) {
    int row = rowbase + mf * 16 + lg * 4;     // 4 consecutive rows, same 64-tile
    int bidx = row >> 13, kib = row & 8191;
    int tile = kib >> 6, kk = kib & 63;
#pragma unroll
    for (int nf = 0; nf < 8; ++nf) {
      int c = cb + nf * 16 + lr;
      S4 st;
      st.x = f2bf(acc[mf][nf][0]); st.y = f2bf(acc[mf][nf][1]);
      st.z = f2bf(acc[mf][nf][2]); st.w = f2bf(acc[mf][nf][3]);
      *(S4*)(vt + (((size_t)bidx * 128 + tile) * CC + c) * 64 + kk) = st;
    }
  }
}

// ---------------- flash attention (k-split): partials or direct xr ----------
// block = 512 thr (8 waves), QB=128 q rows, 64-key tiles, keys split by gridz
__global__ __launch_bounds__(512, 4)
void k_attn(const short* __restrict__ xq, const short* __restrict__ xk,
            const short* __restrict__ vt, float* __restrict__ xr,
            short* __restrict__ po, float* __restrict__ pm,
            float* __restrict__ pl, int nsplit) {
  __shared__ char Kt[8192];     // [64 key][64 d] bf16, chunk-swizzled
  __shared__ char Vt[32768];    // [256 c][64 key] bf16, chunk-swizzled
  __shared__ char Pb[16384];    // per-wave [16 q][64 key] bf16, chunk-swizzled
  const int tid = threadIdx.x;
  const int lane = tid & 63, w = tid >> 6;
  const int lr = lane & 15, lg = lane >> 4;
  const int b = blockIdx.y, qt = blockIdx.x, kz = blockIdx.z;
  const int kpb = (NK / 64) / nsplit;          // key tiles per block

  bf16x8 qa[2];
  {
    const short* qrow = xq + (size_t)(b * NQ + qt * 128 + w * 16 + lr) * C4;
    qa[0] = *(const bf16x8*)(qrow + lg * 8);
    qa[1] = *(const bf16x8*)(qrow + 32 + lg * 8);
  }
  f32x4 o[16] = {};
  float m[4] = {-1e30f, -1e30f, -1e30f, -1e30f};
  float l[4] = {};
  char* pb = Pb + w * 2048;
  const short* kbase = xk + (size_t)b * NK * C4;
  const short* vbase = vt + (size_t)b * 128 * 16384;

#pragma unroll 1
  for (int kt = kz * kpb; kt < (kz + 1) * kpb; ++kt) {
    // ---- stage K tile (8KB) and V^T tile (32KB), XOR chunk swizzle
    {
      const short* ks = kbase + kt * 64 * C4;
      {
        int id = tid, row = id >> 3, c = id & 7;
        uint4 d = *(const uint4*)(ks + row * 64 + c * 8);
        *(uint4*)(Kt + row * 128 + ((c ^ (row & 7)) << 4)) = d;
      }
      const short* vs = vbase + kt * 16384;
#pragma unroll
      for (int j = 0; j < 4; ++j) {
        int id = j * 512 + tid, row = id >> 3, c = id & 7;
        uint4 d = *(const uint4*)(vs + id * 8);
        *(uint4*)(Vt + row * 128 + ((c ^ (row & 7)) << 4)) = d;
      }
    }
    __syncthreads();
    // ---- S = Q K^T (16 q-rows per wave x 64 keys)
    f32x4 s[4] = {};
#pragma unroll
    for (int nf = 0; nf < 4; ++nf) {
      int key = nf * 16 + lr;
#pragma unroll
      for (int kf = 0; kf < 2; ++kf) {
        int ch = kf * 4 + lg;
        bf16x8 kb2 = *(const bf16x8*)(Kt + key * 128 + ((ch ^ (key & 7)) << 4));
        s[nf] = mfma16(qa[kf], kb2, s[nf]);
      }
    }
    // ---- online softmax (rows q = lg*4 + r live in lanes sharing lg)
    float tmax[4], alpha[4], rsum[4];
#pragma unroll
    for (int r = 0; r < 4; ++r)
      tmax[r] = fmaxf(fmaxf(s[0][r], s[1][r]), fmaxf(s[2][r], s[3][r]));
#pragma unroll
    for (int msk = 1; msk <= 8; msk <<= 1)
#pragma unroll
      for (int r = 0; r < 4; ++r)
        tmax[r] = fmaxf(tmax[r], __shfl_xor(tmax[r], msk));
#pragma unroll
    for (int r = 0; r < 4; ++r) {
      float mn = fmaxf(m[r], tmax[r]);
      alpha[r] = __expf(m[r] - mn);
      m[r] = mn;
      rsum[r] = 0.f;
    }
#pragma unroll
    for (int nf = 0; nf < 4; ++nf)
#pragma unroll
      for (int r = 0; r < 4; ++r) {
        float p = __expf(s[nf][r] - m[r]);
        s[nf][r] = p;
        rsum[r] += p;
      }
#pragma unroll
    for (int msk = 1; msk <= 8; msk <<= 1)
#pragma unroll
      for (int r = 0; r < 4; ++r)
        rsum[r] += __shfl_xor(rsum[r], msk);
#pragma unroll
    for (int r = 0; r < 4; ++r)
      l[r] = l[r] * alpha[r] + rsum[r];
#pragma unroll
    for (int cf = 0; cf < 16; ++cf) {
      f32x4 t = o[cf];
      t[0] *= alpha[0]; t[1] *= alpha[1]; t[2] *= alpha[2]; t[3] *= alpha[3];
      o[cf] = t;
    }
    // ---- P (D-frag layout) -> per-wave LDS, re-read as A-frag
#pragma unroll
    for (int nf = 0; nf < 4; ++nf)
#pragma unroll
      for (int r = 0; r < 4; ++r) {
        int qq = lg * 4 + r, key = nf * 16 + lr;
        *(short*)(pb + qq * 128 + (((key >> 3) ^ (qq & 7)) << 4) + (key & 7) * 2) =
            f2bf(s[nf][r]);
      }
    asm volatile("s_waitcnt lgkmcnt(0)" ::: "memory");
    bf16x8 pa[2];
#pragma unroll
    for (int kf = 0; kf < 2; ++kf) {
      int ch = kf * 4 + lg;
      pa[kf] = *(const bf16x8*)(pb + lr * 128 + ((ch ^ (lr & 7)) << 4));
    }
    // ---- O += P V
#pragma unroll
    for (int cf = 0; cf < 16; ++cf) {
      int c = cf * 16 + lr;
#pragma unroll
      for (int kf = 0; kf < 2; ++kf) {
        int ch = kf * 4 + lg;
        bf16x8 vb = *(const bf16x8*)(Vt + c * 128 + ((ch ^ (c & 7)) << 4));
        o[cf] = mfma16(pa[kf], vb, o[cf]);
      }
    }
    __syncthreads();
  }
  // ---- epilogue: direct xr (nsplit==1) or raw partials (nsplit>1)
  if (nsplit == 1) {
    float inv[4];
#pragma unroll
    for (int r = 0; r < 4; ++r) inv[r] = 1.f / l[r];
#pragma unroll
    for (int cf = 0; cf < 16; ++cf)
#pragma unroll
      for (int r = 0; r < 4; ++r) {
        int row = qt * 128 + w * 16 + lg * 4 + r;
        xr[((size_t)b * NQ + row) * CC + cf * 16 + lr] = o[cf][r] * inv[r];
      }
  } else {
#pragma unroll
    for (int r = 0; r < 4; ++r) {
      int grow = b * NQ + qt * 128 + w * 16 + lg * 4 + r;
      if (lr == 0) {
        pm[(size_t)kz * NROWS + grow] = m[r];
        pl[(size_t)kz * NROWS + grow] = l[r];
      }
#pragma unroll
      for (int cf = 0; cf < 16; ++cf)
        po[((size_t)kz * NROWS + grow) * CC + cf * 16 + lr] = f2bf(o[cf][r]);
    }
  }
}

// ---------------- combine 4 k-split partials -> xr ---------------------------
__global__ __launch_bounds__(256)
void k_combine(const short* __restrict__ po, const float* __restrict__ pm,
               const float* __restrict__ pl, float* __restrict__ xr) {
  int t = blockIdx.x * 256 + threadIdx.x;      // NROWS*64 quads
  int row = t >> 6, cq = (t & 63) * 4;
  float mi[4], li[4];
#pragma unroll
  for (int i = 0; i < 4; ++i) {
    mi[i] = pm[(size_t)i * NROWS + row];
    li[i] = pl[(size_t)i * NROWS + row];
  }
  float M = fmaxf(fmaxf(mi[0], mi[1]), fmaxf(mi[2], mi[3]));
  float wi[4], L = 0.f;
#pragma unroll
  for (int i = 0; i < 4; ++i) { wi[i] = __expf(mi[i] - M); L += li[i] * wi[i]; }
  float invL = 1.f / L;
  float a0 = 0, a1 = 0, a2 = 0, a3 = 0;
#pragma unroll
  for (int i = 0; i < 4; ++i) {
    S4 v = *(const S4*)(po + ((size_t)i * NROWS + row) * CC + cq);
    a0 += bf2f(v.x) * wi[i]; a1 += bf2f(v.y) * wi[i];
    a2 += bf2f(v.z) * wi[i]; a3 += bf2f(v.w) * wi[i];
  }
  float4 r; r.x = a0 * invL; r.y = a1 * invL; r.z = a2 * invL; r.w = a3 * invL;
  *(float4*)(xr + (size_t)row * CC + cq) = r;
}

// ---------------- epilogue: out = relu(BN((q - xr) wt^T + bt)) + q -----------
__global__ __launch_bounds__(256)
void k_epilogue(const float* __restrict__ q, const float* __restrict__ xr,
                const short* __restrict__ wtb, const float* __restrict__ scale,
                const float* __restrict__ bias, float* __restrict__ out) {
  const int lane = threadIdx.x & 63, w = threadIdx.x >> 6;
  const int rowbase = blockIdx.x * 128 + w * 32;
  const int cb = blockIdx.y * 128;
  const int lr = lane & 15, lg = lane >> 4;
  f32x4 acc[2][8] = {};
#pragma unroll
  for (int kf = 0; kf < 8; ++kf) {
    bf16x8 a[2];
#pragma unroll
    for (int mf = 0; mf < 2; ++mf) {
      size_t base = (size_t)(rowbase + mf * 16 + lr) * CC + kf * 32 + lg * 8;
      float4 q0 = *(const float4*)(q + base), q1 = *(const float4*)(q + base + 4);
      float4 r0 = *(const float4*)(xr + base), r1 = *(const float4*)(xr + base + 4);
      bf16x8 t;
      t[0] = f2bf(q0.x - r0.x); t[1] = f2bf(q0.y - r0.y);
      t[2] = f2bf(q0.z - r0.z); t[3] = f2bf(q0.w - r0.w);
      t[4] = f2bf(q1.x - r1.x); t[5] = f2bf(q1.y - r1.y);
      t[6] = f2bf(q1.z - r1.z); t[7] = f2bf(q1.w - r1.w);
      a[mf] = t;
    }
#pragma unroll
    for (int nf = 0; nf < 8; ++nf) {
      bf16x8 b = *(const bf16x8*)(wtb + (size_t)(cb + nf * 16 + lr) * CC + kf * 32 + lg * 8);
      acc[0][nf] = mfma16(a[0], b, acc[0][nf]);
      acc[1][nf] = mfma16(a[1], b, acc[1][nf]);
    }
  }
#pragma unroll
  for (int nf = 0; nf < 8; ++nf) {
    int c = cb + nf * 16 + lr;
    float sc = scale[c], bi = bias[c];
#pragma unroll
    for (int mf = 0; mf < 2; ++mf)
#pragma unroll
      for (int r = 0; r < 4; ++r) {
        int row = rowbase + mf * 16 + lg * 4 + r;
        float y = acc[mf][nf][r] * sc + bi;
        y = fmaxf(y, 0.f) + q[(size_t)row * CC + c];
        out[(size_t)row * CC + c] = y;
      }
  }
}

// ---------------- launch -----------------------------------------------------
extern "C" void kernel_launch(void* const* d_in, const int* in_sizes, int n_in,
                              void* d_out, int out_size, void* d_ws, size_t ws_size,
                              hipStream_t stream) {
  const float* q     = (const float*)d_in[0];
  const float* kv    = (const float*)d_in[1];
  const float* wq    = (const float*)d_in[2];
  const float* wk    = (const float*)d_in[3];
  const float* wv    = (const float*)d_in[4];
  const float* wt    = (const float*)d_in[5];
  const float* bt    = (const float*)d_in[6];
  const float* gmm   = (const float*)d_in[7];
  const float* bet   = (const float*)d_in[8];
  const float* rmean = (const float*)d_in[9];
  const float* rvar  = (const float*)d_in[10];
  float* out = (float*)d_out;
  char* ws = (char*)d_ws;

  short* wqb  = (short*)(ws + 0);         // 32 KB
  short* wkb  = (short*)(ws + 32768);     // 32 KB
  short* wvb  = (short*)(ws + 65536);     // 128 KB
  short* wtb  = (short*)(ws + 196608);    // 128 KB
  float* scale= (float*)(ws + 327680);    // 1 KB
  float* bias = (float*)(ws + 328704);    // 1 KB
  short* xq   = (short*)(ws + 329728);    // 2 MB
  short* xk   = (short*)(ws + 2426880);   // 2 MB
  short* vt   = (short*)(ws + 4524032);   // 8 MB
  float* xr   = (float*)(ws + 12912640);  // 16 MB
  short* po   = (short*)(ws + 29689856);  // 32 MB (4 x 16384 x 256 bf16)
  float* pm   = (float*)(ws + 63244288);  // 256 KB
  float* pl   = (float*)(ws + 63506432);  // 256 KB
  const size_t NEED = 63768576;
  const int nsplit = (ws_size >= NEED) ? 4 : 1;

  k_setup<<<256, 256, 0, stream>>>(wq, wk, wv, wt, bt, gmm, bet, rmean, rvar,
                                   wqb, wkb, wvb, wtb, scale, bias);
  k_projqk<<<dim3(128, 2), 256, 0, stream>>>(q, kv, wqb, wkb, xq, xk);
  k_projv<<<dim3(128, 2), 256, 0, stream>>>(kv, wvb, vt);
  k_attn<<<dim3(64, 2, nsplit), 512, 0, stream>>>(xq, xk, vt, xr, po, pm, pl, nsplit);
  if (nsplit > 1)
    k_combine<<<NROWS * 64 / 256, 256, 0, stream>>>(po, pm, pl, xr);
  k_epilogue<<<dim3(128, 2), 256, 0, stream>>>(q, xr, wtb, scale, bias, out);
}

// Round 3
// 182.643 us; speedup vs baseline: 1.9855x; 1.4494x over previous
//
#include <hip/hip_runtime.h>
#include <hip/hip_bf16.h>

#define DEVINL __device__ __forceinline__

typedef short bf16x8 __attribute__((ext_vector_type(8)));
typedef float f32x4  __attribute__((ext_vector_type(4)));
typedef float f32x16 __attribute__((ext_vector_type(16)));
typedef unsigned int uint2v __attribute__((ext_vector_type(2)));

struct alignas(8) S4 { short x, y, z, w; };

DEVINL short f2bf(float f) {
  __hip_bfloat16 h = __float2bfloat16(f);
  short s; __builtin_memcpy(&s, &h, 2); return s;
}
DEVINL float bf2f(short s) {
  unsigned u = ((unsigned)(unsigned short)s) << 16;
  float f; __builtin_memcpy(&f, &u, 4); return f;
}

DEVINL f32x4 mfma16(bf16x8 a, bf16x8 b, f32x4 c) {
  return __builtin_amdgcn_mfma_f32_16x16x32_bf16(a, b, c, 0, 0, 0);
}
DEVINL f32x16 mfma32(bf16x8 a, bf16x8 b, f32x16 c) {
  return __builtin_amdgcn_mfma_f32_32x32x16_bf16(a, b, c, 0, 0, 0);
}

// async global->LDS, 16B per lane; LDS dest is wave-uniform base (+lane*16 by HW)
DEVINL void gld_lds16(const void* gptr, void* lptr) {
  __builtin_amdgcn_global_load_lds(
      (const __attribute__((address_space(1))) unsigned int*)gptr,
      (__attribute__((address_space(3))) unsigned int*)lptr, 16, 0, 0);
}

#define CC 256
#define C4 64
#define BB 2
#define NQ 8192
#define NK 8192
#define NROWS (BB * NQ)
#define DT 10.0f            // defer-max threshold (log2 domain)
#define LOG2E 1.44269504f

// ---------------- setup: weights -> bf16 (wq pre-scaled by log2e), BN fold ---
__global__ void k_setup(const float* __restrict__ wq, const float* __restrict__ wk,
                        const float* __restrict__ wv, const float* __restrict__ wt,
                        const float* __restrict__ bt, const float* __restrict__ gmm,
                        const float* __restrict__ bet, const float* __restrict__ rmean,
                        const float* __restrict__ rvar,
                        short* __restrict__ wqb, short* __restrict__ wkb,
                        short* __restrict__ wvb, short* __restrict__ wtb,
                        float* __restrict__ scale, float* __restrict__ bias) {
  int i = blockIdx.x * 256 + threadIdx.x;
  if (i < C4 * CC) { wqb[i] = f2bf(wq[i] * LOG2E); wkb[i] = f2bf(wk[i]); }
  if (i < CC * CC) { wvb[i] = f2bf(wv[i]); wtb[i] = f2bf(wt[i]); }
  if (i < CC) {
    float s = gmm[i] * rsqrtf(rvar[i] + 1e-5f);
    scale[i] = s;
    bias[i]  = (bt[i] - rmean[i]) * s + bet[i];
  }
}

// ---------------- proj q/k: xq linear [M,64]; xk chunk-swizzled rows ---------
__global__ __launch_bounds__(256)
void k_projqk(const float* __restrict__ q, const float* __restrict__ kv,
              const short* __restrict__ wqb, const short* __restrict__ wkb,
              short* __restrict__ xq, short* __restrict__ xk) {
  const float* A; const short* W; short* O;
  const bool swz = (blockIdx.y == 1);
  if (!swz) { A = q; W = wqb; O = xq; } else { A = kv; W = wkb; O = xk; }
  const int lane = threadIdx.x & 63, w = threadIdx.x >> 6;
  const int rowbase = blockIdx.x * 128 + w * 32;
  const int lr = lane & 15, lg = lane >> 4;
  f32x4 acc[2][4] = {};
#pragma unroll
  for (int kf = 0; kf < 8; ++kf) {
    bf16x8 a[2];
#pragma unroll
    for (int mf = 0; mf < 2; ++mf) {
      const float* p = A + (size_t)(rowbase + mf * 16 + lr) * CC + kf * 32 + lg * 8;
      float4 x0 = *(const float4*)p, x1 = *(const float4*)(p + 4);
      bf16x8 t;
      t[0] = f2bf(x0.x); t[1] = f2bf(x0.y); t[2] = f2bf(x0.z); t[3] = f2bf(x0.w);
      t[4] = f2bf(x1.x); t[5] = f2bf(x1.y); t[6] = f2bf(x1.z); t[7] = f2bf(x1.w);
      a[mf] = t;
    }
#pragma unroll
    for (int nf = 0; nf < 4; ++nf) {
      bf16x8 b = *(const bf16x8*)(W + (size_t)(nf * 16 + lr) * CC + kf * 32 + lg * 8);
      acc[0][nf] = mfma16(a[0], b, acc[0][nf]);
      acc[1][nf] = mfma16(a[1], b, acc[1][nf]);
    }
  }
#pragma unroll
  for (int mf = 0; mf < 2; ++mf)
#pragma unroll
    for (int nf = 0; nf < 4; ++nf)
#pragma unroll
      for (int r = 0; r < 4; ++r) {
        int row = rowbase + mf * 16 + lg * 4 + r;
        int d = nf * 16 + lr;
        int off = swz ? ((((d >> 3) ^ (row & 7)) << 3) + (d & 7)) : d;
        O[(size_t)row * C4 + off] = f2bf(acc[mf][nf][r]);
      }
}

// ---------------- proj v: vt[b][tile][c][key] bf16, chunk-swizzled rows ------
__global__ __launch_bounds__(256)
void k_projv(const float* __restrict__ kv, const short* __restrict__ wvb,
             short* __restrict__ vt) {
  const int lane = threadIdx.x & 63, w = threadIdx.x >> 6;
  const int rowbase = blockIdx.x * 128 + w * 32;
  const int cb = blockIdx.y * 128;
  const int lr = lane & 15, lg = lane >> 4;
  f32x4 acc[2][8] = {};
#pragma unroll
  for (int kf = 0; kf < 8; ++kf) {
    bf16x8 a[2];
#pragma unroll
    for (int mf = 0; mf < 2; ++mf) {
      const float* p = kv + (size_t)(rowbase + mf * 16 + lr) * CC + kf * 32 + lg * 8;
      float4 x0 = *(const float4*)p, x1 = *(const float4*)(p + 4);
      bf16x8 t;
      t[0] = f2bf(x0.x); t[1] = f2bf(x0.y); t[2] = f2bf(x0.z); t[3] = f2bf(x0.w);
      t[4] = f2bf(x1.x); t[5] = f2bf(x1.y); t[6] = f2bf(x1.z); t[7] = f2bf(x1.w);
      a[mf] = t;
    }
#pragma unroll
    for (int nf = 0; nf < 8; ++nf) {
      bf16x8 b = *(const bf16x8*)(wvb + (size_t)(cb + nf * 16 + lr) * CC + kf * 32 + lg * 8);
      acc[0][nf] = mfma16(a[0], b, acc[0][nf]);
      acc[1][nf] = mfma16(a[1], b, acc[1][nf]);
    }
  }
#pragma unroll
  for (int mf = 0; mf < 2; ++mf) {
    int row = rowbase + mf * 16 + lg * 4;     // 4 consecutive keys, same 64-tile
    int bidx = row >> 13, kib = row & 8191;
    int tile = kib >> 6, kk = kib & 63;       // kk % 4 == 0, kk%8 in {0,4}
#pragma unroll
    for (int nf = 0; nf < 8; ++nf) {
      int c = cb + nf * 16 + lr;
      S4 st;
      st.x = f2bf(acc[mf][nf][0]); st.y = f2bf(acc[mf][nf][1]);
      st.z = f2bf(acc[mf][nf][2]); st.w = f2bf(acc[mf][nf][3]);
      int off = (((kk >> 3) ^ (c & 7)) << 3) + (kk & 7);
      *(S4*)(vt + (((size_t)bidx * 128 + tile) * CC + c) * 64 + off) = st;
    }
  }
}

// ---------------- flash attention: 32x32 swapped, in-register softmax --------
// 256 thr (4 waves), 32 q-rows/wave, QB=128, KB=64, k-split by gridz
__global__ __launch_bounds__(256, 2)
void k_attn(const short* __restrict__ xq, const short* __restrict__ xk,
            const short* __restrict__ vt, float* __restrict__ xr,
            short* __restrict__ po, float* __restrict__ pm,
            float* __restrict__ pl, int nsplit) {
  __shared__ char Lds[40960];
  char* Kt = Lds;           // 8 KB  [64 key][8 x 16B slots] (pre-swizzled)
  char* Vt = Lds + 8192;    // 32 KB [256 c ][8 x 16B slots] (pre-swizzled)
  const int tid = threadIdx.x;
  const int ln = tid & 63, w = tid >> 6;
  const int qcol = ln & 31, hi = ln >> 5;
  const int b = blockIdx.y, qt = blockIdx.x, kz = blockIdx.z;
  const int kpb = (NK / 64) / nsplit;
  const int kt0 = kz * kpb, kt1 = kt0 + kpb;

  // Q as B-fragments (col=q, k=d), from linear xq (already log2e-scaled)
  bf16x8 qb[4];
  {
    const short* qrow = xq + (size_t)(b * NQ + qt * 128 + w * 32 + qcol) * C4;
#pragma unroll
    for (int ds = 0; ds < 4; ++ds)
      qb[ds] = *(const bf16x8*)(qrow + ds * 16 + hi * 8);
  }
  f32x16 o[8] = {};
  float m = -1e30f, lsum = 0.f;

  const char* kgbase = (const char*)(xk + (size_t)b * NK * C4);
  const char* vgbase = (const char*)(vt + (size_t)b * 128 * 16384);

  auto stage = [&](int kt) {
    const char* ks = kgbase + (size_t)kt * 8192;
    const char* vs = vgbase + (size_t)kt * 32768;
#pragma unroll
    for (int i = 0; i < 2; ++i)
      gld_lds16(ks + (w * 2 + i) * 1024 + ln * 16, Kt + (w * 2 + i) * 1024);
#pragma unroll
    for (int i = 0; i < 8; ++i)
      gld_lds16(vs + (w * 8 + i) * 1024 + ln * 16, Vt + (w * 8 + i) * 1024);
  };

  stage(kt0);
#pragma unroll 1
  for (int kt = kt0; kt < kt1; ++kt) {
    __syncthreads();          // stage complete (compiler drains vmcnt)
    // ---- S^T = K x Q^T : lane holds 32 key-values for q = qcol (pair w/ ln^32)
    f32x16 s[2] = {};
#pragma unroll
    for (int kb = 0; kb < 2; ++kb) {
      int key = kb * 32 + qcol;
#pragma unroll
      for (int ds = 0; ds < 4; ++ds) {
        int cc = ds * 2 + hi;
        bf16x8 ka = *(const bf16x8*)(Kt + key * 128 + ((cc ^ (key & 7)) << 4));
        s[kb] = mfma32(ka, qb[ds], s[kb]);
      }
    }
    // ---- online softmax, fully in-register (log2 domain), defer-max
    float pmax = s[0][0];
#pragma unroll
    for (int r = 1; r < 16; ++r) pmax = fmaxf(pmax, s[0][r]);
#pragma unroll
    for (int r = 0; r < 16; ++r) pmax = fmaxf(pmax, s[1][r]);
    pmax = fmaxf(pmax, __shfl_xor(pmax, 32));
    bool grow = pmax > m + DT;
    if (__any(grow)) {
      float alpha = grow ? exp2f(m - pmax) : 1.f;
      m = grow ? pmax : m;
      lsum *= alpha;
#pragma unroll
      for (int cb = 0; cb < 8; ++cb)
#pragma unroll
        for (int r = 0; r < 16; ++r) o[cb][r] *= alpha;
    }
    float rs = 0.f;
#pragma unroll
    for (int r = 0; r < 16; ++r) { float p = exp2f(s[0][r] - m); s[0][r] = p; rs += p; }
#pragma unroll
    for (int r = 0; r < 16; ++r) { float p = exp2f(s[1][r] - m); s[1][r] = p; rs += p; }
    rs += __shfl_xor(rs, 32);
    lsum += rs;
    // ---- P -> bf16 B-frags via cvt_pk + permlane32_swap (no LDS)
    bf16x8 pb[4];
#pragma unroll
    for (int kb = 0; kb < 2; ++kb) {
      unsigned wv[4], uv[4];
#pragma unroll
      for (int j = 0; j < 4; ++j) {
        asm("v_cvt_pk_bf16_f32 %0, %1, %2"
            : "=v"(wv[j]) : "v"(s[kb][4 * j + 0]), "v"(s[kb][4 * j + 1]));
        asm("v_cvt_pk_bf16_f32 %0, %1, %2"
            : "=v"(uv[j]) : "v"(s[kb][4 * j + 2]), "v"(s[kb][4 * j + 3]));
      }
#pragma unroll
      for (int jj = 0; jj < 2; ++jj) {
        uint2v rw = __builtin_amdgcn_permlane32_swap(wv[2 * jj], wv[2 * jj + 1], false, false);
        uint2v ru = __builtin_amdgcn_permlane32_swap(uv[2 * jj], uv[2 * jj + 1], false, false);
        unsigned tmp[4] = { rw[0], ru[0], rw[1], ru[1] };
        bf16x8 t; __builtin_memcpy(&t, tmp, 16);
        pb[kb * 2 + jj] = t;
      }
    }
    // ---- O^T += V^T x P^T
#pragma unroll
    for (int cb = 0; cb < 8; ++cb) {
      int c = cb * 32 + qcol;
#pragma unroll
      for (int ks = 0; ks < 4; ++ks) {
        int cc = ks * 2 + hi;
        bf16x8 va = *(const bf16x8*)(Vt + c * 128 + ((cc ^ (c & 7)) << 4));
        o[cb] = mfma32(va, pb[ks], o[cb]);
      }
    }
    __syncthreads();          // all reads done; safe to overwrite
    if (kt + 1 < kt1) stage(kt + 1);
  }
  // ---- epilogue: transpose per-wave via LDS scratch, coalesced stores
  char* tb = Lds + w * 4096;  // 4 KB/wave; safe after final barrier
  const size_t rb = (size_t)b * NQ + qt * 128 + w * 32;
  if (nsplit == 1) {
    float inv = 1.f / lsum;
#pragma unroll
    for (int cb = 0; cb < 8; ++cb) {
#pragma unroll
      for (int j = 0; j < 4; ++j) {
        f32x4 v;
        v[0] = o[cb][4 * j + 0] * inv; v[1] = o[cb][4 * j + 1] * inv;
        v[2] = o[cb][4 * j + 2] * inv; v[3] = o[cb][4 * j + 3] * inv;
        *(f32x4*)(tb + qcol * 128 + (((2 * j + hi) ^ (qcol & 7)) << 4)) = v;
      }
#pragma unroll
      for (int jr = 0; jr < 4; ++jr) {
        int qr = jr * 8 + (ln >> 3), cc = ln & 7;
        f32x4 v = *(const f32x4*)(tb + qr * 128 + ((cc ^ (qr & 7)) << 4));
        *(f32x4*)(xr + (rb + qr) * CC + cb * 32 + cc * 4) = v;
      }
    }
  } else {
#pragma unroll
    for (int cb = 0; cb < 8; ++cb) {
#pragma unroll
      for (int j = 0; j < 4; ++j) {
        f32x4 v;
        v[0] = o[cb][4 * j + 0]; v[1] = o[cb][4 * j + 1];
        v[2] = o[cb][4 * j + 2]; v[3] = o[cb][4 * j + 3];
        *(f32x4*)(tb + qcol * 128 + (((2 * j + hi) ^ (qcol & 7)) << 4)) = v;
      }
#pragma unroll
      for (int jr = 0; jr < 4; ++jr) {
        int qr = jr * 8 + (ln >> 3), cc = ln & 7;
        f32x4 v = *(const f32x4*)(tb + qr * 128 + ((cc ^ (qr & 7)) << 4));
        S4 sv; sv.x = f2bf(v[0]); sv.y = f2bf(v[1]); sv.z = f2bf(v[2]); sv.w = f2bf(v[3]);
        *(S4*)(po + ((size_t)kz * NROWS + rb + qr) * CC + cb * 32 + cc * 4) = sv;
      }
    }
    if (ln < 32) {
      size_t g = (size_t)kz * NROWS + rb + qcol;
      pm[g] = m;
      pl[g] = lsum;
    }
  }
}

// ---------------- combine 4 k-split partials -> xr (log2 domain) -------------
__global__ __launch_bounds__(256)
void k_combine(const short* __restrict__ po, const float* __restrict__ pm,
               const float* __restrict__ pl, float* __restrict__ xr) {
  int t = blockIdx.x * 256 + threadIdx.x;      // NROWS*64 quads
  int row = t >> 6, cq = (t & 63) * 4;
  float mi[4], li[4];
#pragma unroll
  for (int i = 0; i < 4; ++i) {
    mi[i] = pm[(size_t)i * NROWS + row];
    li[i] = pl[(size_t)i * NROWS + row];
  }
  float M = fmaxf(fmaxf(mi[0], mi[1]), fmaxf(mi[2], mi[3]));
  float wi[4], L = 0.f;
#pragma unroll
  for (int i = 0; i < 4; ++i) { wi[i] = exp2f(mi[i] - M); L += li[i] * wi[i]; }
  float invL = 1.f / L;
  float a0 = 0, a1 = 0, a2 = 0, a3 = 0;
#pragma unroll
  for (int i = 0; i < 4; ++i) {
    S4 v = *(const S4*)(po + ((size_t)i * NROWS + row) * CC + cq);
    a0 += bf2f(v.x) * wi[i]; a1 += bf2f(v.y) * wi[i];
    a2 += bf2f(v.z) * wi[i]; a3 += bf2f(v.w) * wi[i];
  }
  float4 r; r.x = a0 * invL; r.y = a1 * invL; r.z = a2 * invL; r.w = a3 * invL;
  *(float4*)(xr + (size_t)row * CC + cq) = r;
}

// ---------------- epilogue: out = relu(BN((q - xr) wt^T + bt)) + q -----------
__global__ __launch_bounds__(256)
void k_epilogue(const float* __restrict__ q, const float* __restrict__ xr,
                const short* __restrict__ wtb, const float* __restrict__ scale,
                const float* __restrict__ bias, float* __restrict__ out) {
  const int lane = threadIdx.x & 63, w = threadIdx.x >> 6;
  const int rowbase = blockIdx.x * 128 + w * 32;
  const int cb = blockIdx.y * 128;
  const int lr = lane & 15, lg = lane >> 4;
  f32x4 acc[2][8] = {};
#pragma unroll
  for (int kf = 0; kf < 8; ++kf) {
    bf16x8 a[2];
#pragma unroll
    for (int mf = 0; mf < 2; ++mf) {
      size_t base = (size_t)(rowbase + mf * 16 + lr) * CC + kf * 32 + lg * 8;
      float4 q0 = *(const float4*)(q + base), q1 = *(const float4*)(q + base + 4);
      float4 r0 = *(const float4*)(xr + base), r1 = *(const float4*)(xr + base + 4);
      bf16x8 t;
      t[0] = f2bf(q0.x - r0.x); t[1] = f2bf(q0.y - r0.y);
      t[2] = f2bf(q0.z - r0.z); t[3] = f2bf(q0.w - r0.w);
      t[4] = f2bf(q1.x - r1.x); t[5] = f2bf(q1.y - r1.y);
      t[6] = f2bf(q1.z - r1.z); t[7] = f2bf(q1.w - r1.w);
      a[mf] = t;
    }
#pragma unroll
    for (int nf = 0; nf < 8; ++nf) {
      bf16x8 b = *(const bf16x8*)(wtb + (size_t)(cb + nf * 16 + lr) * CC + kf * 32 + lg * 8);
      acc[0][nf] = mfma16(a[0], b, acc[0][nf]);
      acc[1][nf] = mfma16(a[1], b, acc[1][nf]);
    }
  }
#pragma unroll
  for (int nf = 0; nf < 8; ++nf) {
    int c = cb + nf * 16 + lr;
    float sc = scale[c], bi = bias[c];
#pragma unroll
    for (int mf = 0; mf < 2; ++mf)
#pragma unroll
      for (int r = 0; r < 4; ++r) {
        int row = rowbase + mf * 16 + lg * 4 + r;
        float y = acc[mf][nf][r] * sc + bi;
        y = fmaxf(y, 0.f) + q[(size_t)row * CC + c];
        out[(size_t)row * CC + c] = y;
      }
  }
}

// ---------------- launch -----------------------------------------------------
extern "C" void kernel_launch(void* const* d_in, const int* in_sizes, int n_in,
                              void* d_out, int out_size, void* d_ws, size_t ws_size,
                              hipStream_t stream) {
  const float* q     = (const float*)d_in[0];
  const float* kv    = (const float*)d_in[1];
  const float* wq    = (const float*)d_in[2];
  const float* wk    = (const float*)d_in[3];
  const float* wv    = (const float*)d_in[4];
  const float* wt    = (const float*)d_in[5];
  const float* bt    = (const float*)d_in[6];
  const float* gmm   = (const float*)d_in[7];
  const float* bet   = (const float*)d_in[8];
  const float* rmean = (const float*)d_in[9];
  const float* rvar  = (const float*)d_in[10];
  float* out = (float*)d_out;
  char* ws = (char*)d_ws;

  short* wqb  = (short*)(ws + 0);         // 32 KB
  short* wkb  = (short*)(ws + 32768);     // 32 KB
  short* wvb  = (short*)(ws + 65536);     // 128 KB
  short* wtb  = (short*)(ws + 196608);    // 128 KB
  float* scale= (float*)(ws + 327680);    // 1 KB
  float* bias = (float*)(ws + 328704);    // 1 KB
  short* xq   = (short*)(ws + 329728);    // 2 MB
  short* xk   = (short*)(ws + 2426880);   // 2 MB
  short* vt   = (short*)(ws + 4524032);   // 8 MB
  float* xr   = (float*)(ws + 12912640);  // 16 MB
  short* po   = (short*)(ws + 29689856);  // 32 MB (4 x 16384 x 256 bf16)
  float* pm   = (float*)(ws + 63244288);  // 256 KB
  float* pl   = (float*)(ws + 63506432);  // 256 KB
  const size_t NEED = 63768576;
  const int nsplit = (ws_size >= NEED) ? 4 : 1;

  k_setup<<<256, 256, 0, stream>>>(wq, wk, wv, wt, bt, gmm, bet, rmean, rvar,
                                   wqb, wkb, wvb, wtb, scale, bias);
  k_projqk<<<dim3(128, 2), 256, 0, stream>>>(q, kv, wqb, wkb, xq, xk);
  k_projv<<<dim3(128, 2), 256, 0, stream>>>(kv, wvb, vt);
  k_attn<<<dim3(64, 2, nsplit), 256, 0, stream>>>(xq, xk, vt, xr, po, pm, pl, nsplit);
  if (nsplit > 1)
    k_combine<<<NROWS * 64 / 256, 256, 0, stream>>>(po, pm, pl, xr);
  k_epilogue<<<dim3(128, 2), 256, 0, stream>>>(q, xr, wtb, scale, bias, out);
}

// Round 4
// 174.682 us; speedup vs baseline: 2.0760x; 1.0456x over previous
//
#include <hip/hip_runtime.h>
#include <hip/hip_bf16.h>

#define DEVINL __device__ __forceinline__

typedef short bf16x8 __attribute__((ext_vector_type(8)));
typedef float f32x4  __attribute__((ext_vector_type(4)));
typedef float f32x16 __attribute__((ext_vector_type(16)));
typedef unsigned int uint2v __attribute__((ext_vector_type(2)));

struct alignas(8) S4 { short x, y, z, w; };

DEVINL short f2bf(float f) {
  __hip_bfloat16 h = __float2bfloat16(f);
  short s; __builtin_memcpy(&s, &h, 2); return s;
}
DEVINL float bf2f(short s) {
  unsigned u = ((unsigned)(unsigned short)s) << 16;
  float f; __builtin_memcpy(&f, &u, 4); return f;
}

DEVINL f32x4 mfma16(bf16x8 a, bf16x8 b, f32x4 c) {
  return __builtin_amdgcn_mfma_f32_16x16x32_bf16(a, b, c, 0, 0, 0);
}
DEVINL f32x16 mfma32(bf16x8 a, bf16x8 b, f32x16 c) {
  return __builtin_amdgcn_mfma_f32_32x32x16_bf16(a, b, c, 0, 0, 0);
}

// async global->LDS, 16B per lane; LDS dest is wave-uniform base (+lane*16 by HW)
DEVINL void gld_lds16(const void* gptr, void* lptr) {
  __builtin_amdgcn_global_load_lds(
      (const __attribute__((address_space(1))) unsigned int*)gptr,
      (__attribute__((address_space(3))) unsigned int*)lptr, 16, 0, 0);
}

#define CC 256
#define C4 64
#define BB 2
#define NQ 8192
#define NK 8192
#define NROWS (BB * NQ)
#define DT 10.0f            // defer-max threshold (log2 domain)
#define LOG2E 1.44269504f

// ---------------- setup: weights -> bf16 (wq pre-scaled by log2e), BN fold ---
__global__ void k_setup(const float* __restrict__ wq, const float* __restrict__ wk,
                        const float* __restrict__ wv, const float* __restrict__ wt,
                        const float* __restrict__ bt, const float* __restrict__ gmm,
                        const float* __restrict__ bet, const float* __restrict__ rmean,
                        const float* __restrict__ rvar,
                        short* __restrict__ wqb, short* __restrict__ wkb,
                        short* __restrict__ wvb, short* __restrict__ wtb,
                        float* __restrict__ scale, float* __restrict__ bias) {
  int i = blockIdx.x * 256 + threadIdx.x;
  if (i < C4 * CC) { wqb[i] = f2bf(wq[i] * LOG2E); wkb[i] = f2bf(wk[i]); }
  if (i < CC * CC) { wvb[i] = f2bf(wv[i]); wtb[i] = f2bf(wt[i]); }
  if (i < CC) {
    float s = gmm[i] * rsqrtf(rvar[i] + 1e-5f);
    scale[i] = s;
    bias[i]  = (bt[i] - rmean[i]) * s + bet[i];
  }
}

// ---------------- proj q/k: xq linear [M,64]; xk chunk-swizzled rows ---------
// 16 rows/wave, 64 rows/block -> grid (256,2) = 512 blocks (2 waves/SIMD)
__global__ __launch_bounds__(256)
void k_projqk(const float* __restrict__ q, const float* __restrict__ kv,
              const short* __restrict__ wqb, const short* __restrict__ wkb,
              short* __restrict__ xq, short* __restrict__ xk) {
  const float* A; const short* W; short* O;
  const bool swz = (blockIdx.y == 1);
  if (!swz) { A = q; W = wqb; O = xq; } else { A = kv; W = wkb; O = xk; }
  const int lane = threadIdx.x & 63, w = threadIdx.x >> 6;
  const int rowbase = blockIdx.x * 64 + w * 16;
  const int lr = lane & 15, lg = lane >> 4;
  f32x4 acc[4] = {};
#pragma unroll
  for (int kf = 0; kf < 8; ++kf) {
    const float* p = A + (size_t)(rowbase + lr) * CC + kf * 32 + lg * 8;
    float4 x0 = *(const float4*)p, x1 = *(const float4*)(p + 4);
    bf16x8 a;
    a[0] = f2bf(x0.x); a[1] = f2bf(x0.y); a[2] = f2bf(x0.z); a[3] = f2bf(x0.w);
    a[4] = f2bf(x1.x); a[5] = f2bf(x1.y); a[6] = f2bf(x1.z); a[7] = f2bf(x1.w);
#pragma unroll
    for (int nf = 0; nf < 4; ++nf) {
      bf16x8 b = *(const bf16x8*)(W + (size_t)(nf * 16 + lr) * CC + kf * 32 + lg * 8);
      acc[nf] = mfma16(a, b, acc[nf]);
    }
  }
#pragma unroll
  for (int nf = 0; nf < 4; ++nf)
#pragma unroll
    for (int r = 0; r < 4; ++r) {
      int row = rowbase + lg * 4 + r;
      int d = nf * 16 + lr;
      int off = swz ? ((((d >> 3) ^ (row & 7)) << 3) + (d & 7)) : d;
      O[(size_t)row * C4 + off] = f2bf(acc[nf][r]);
    }
}

// ---------------- proj v: vt[b][tile][c][key] bf16, chunk-swizzled rows ------
// 16 rows/wave, 64 rows/block -> grid (256,2) = 512 blocks
__global__ __launch_bounds__(256)
void k_projv(const float* __restrict__ kv, const short* __restrict__ wvb,
             short* __restrict__ vt) {
  const int lane = threadIdx.x & 63, w = threadIdx.x >> 6;
  const int rowbase = blockIdx.x * 64 + w * 16;
  const int cb = blockIdx.y * 128;
  const int lr = lane & 15, lg = lane >> 4;
  f32x4 acc[8] = {};
#pragma unroll
  for (int kf = 0; kf < 8; ++kf) {
    const float* p = kv + (size_t)(rowbase + lr) * CC + kf * 32 + lg * 8;
    float4 x0 = *(const float4*)p, x1 = *(const float4*)(p + 4);
    bf16x8 a;
    a[0] = f2bf(x0.x); a[1] = f2bf(x0.y); a[2] = f2bf(x0.z); a[3] = f2bf(x0.w);
    a[4] = f2bf(x1.x); a[5] = f2bf(x1.y); a[6] = f2bf(x1.z); a[7] = f2bf(x1.w);
#pragma unroll
    for (int nf = 0; nf < 8; ++nf) {
      bf16x8 b = *(const bf16x8*)(wvb + (size_t)(cb + nf * 16 + lr) * CC + kf * 32 + lg * 8);
      acc[nf] = mfma16(a, b, acc[nf]);
    }
  }
  {
    int row = rowbase + lg * 4;               // 4 consecutive keys, same 64-tile
    int bidx = row >> 13, kib = row & 8191;
    int tile = kib >> 6, kk = kib & 63;       // kk % 4 == 0
#pragma unroll
    for (int nf = 0; nf < 8; ++nf) {
      int c = cb + nf * 16 + lr;
      S4 st;
      st.x = f2bf(acc[nf][0]); st.y = f2bf(acc[nf][1]);
      st.z = f2bf(acc[nf][2]); st.w = f2bf(acc[nf][3]);
      int off = (((kk >> 3) ^ (c & 7)) << 3) + (kk & 7);
      *(S4*)(vt + (((size_t)bidx * 128 + tile) * CC + c) * 64 + off) = st;
    }
  }
}

// ---------------- flash attention: 32x32 swapped, in-register softmax --------
// 256 thr (4 waves), 32 q-rows/wave, QB=128, KB=64, k-split by gridz
// double-buffered LDS + counted vmcnt + raw barriers (T3/T4-lite)
__global__ __launch_bounds__(256, 2)
void k_attn(const short* __restrict__ xq, const short* __restrict__ xk,
            const short* __restrict__ vt, float* __restrict__ xr,
            short* __restrict__ po, float* __restrict__ pm,
            float* __restrict__ pl, int nsplit) {
  __shared__ char Lds[81920];   // 2 x (8KB K + 32KB V)
  const int tid = threadIdx.x;
  const int ln = tid & 63, w = tid >> 6;
  const int qcol = ln & 31, hi = ln >> 5;
  const int b = blockIdx.y, qt = blockIdx.x, kz = blockIdx.z;
  const int kpb = (NK / 64) / nsplit;
  const int kt0 = kz * kpb, kt1 = kt0 + kpb;

  // Q as B-fragments (col=q, k=d), from linear xq (already log2e-scaled)
  bf16x8 qb[4];
  {
    const short* qrow = xq + (size_t)(b * NQ + qt * 128 + w * 32 + qcol) * C4;
#pragma unroll
    for (int ds = 0; ds < 4; ++ds)
      qb[ds] = *(const bf16x8*)(qrow + ds * 16 + hi * 8);
  }
  f32x16 o[8] = {};
  float m = -1e30f, lsum = 0.f;

  const char* kgbase = (const char*)(xk + (size_t)b * NK * C4);
  const char* vgbase = (const char*)(vt + (size_t)b * 128 * 16384);

  auto stage = [&](int kt, char* base) {
    const char* ks = kgbase + (size_t)kt * 8192;
    const char* vs = vgbase + (size_t)kt * 32768;
#pragma unroll
    for (int i = 0; i < 2; ++i)
      gld_lds16(ks + (w * 2 + i) * 1024 + ln * 16, base + (w * 2 + i) * 1024);
#pragma unroll
    for (int i = 0; i < 8; ++i)
      gld_lds16(vs + (w * 8 + i) * 1024 + ln * 16, base + 8192 + (w * 8 + i) * 1024);
  };

  stage(kt0, Lds);
#pragma unroll 1
  for (int kt = kt0; kt < kt1; ++kt) {
    char* Kc = Lds + ((kt - kt0) & 1) * 40960;
    char* Vc = Kc + 8192;
    if (kt + 1 < kt1) {
      stage(kt + 1, Lds + ((~(kt - kt0)) & 1) * 40960);
      asm volatile("s_waitcnt vmcnt(10)" ::: "memory");  // cur's 10 loads done
    } else {
      asm volatile("s_waitcnt vmcnt(0)" ::: "memory");
    }
    __builtin_amdgcn_s_barrier();                        // all waves staged cur
    __builtin_amdgcn_sched_barrier(0);
    // ---- S^T = K x Q^T : lane holds 32 key-values for q = qcol
    f32x16 s[2] = {};
#pragma unroll
    for (int kb = 0; kb < 2; ++kb) {
      int key = kb * 32 + qcol;
#pragma unroll
      for (int ds = 0; ds < 4; ++ds) {
        int cc = ds * 2 + hi;
        bf16x8 ka = *(const bf16x8*)(Kc + key * 128 + ((cc ^ (key & 7)) << 4));
        s[kb] = mfma32(ka, qb[ds], s[kb]);
      }
    }
    // ---- online softmax, fully in-register (log2 domain), defer-max
    float pmax = s[0][0];
#pragma unroll
    for (int r = 1; r < 16; ++r) pmax = fmaxf(pmax, s[0][r]);
#pragma unroll
    for (int r = 0; r < 16; ++r) pmax = fmaxf(pmax, s[1][r]);
    pmax = fmaxf(pmax, __shfl_xor(pmax, 32));
    bool grow = pmax > m + DT;
    if (__any(grow)) {
      float alpha = grow ? exp2f(m - pmax) : 1.f;
      m = grow ? pmax : m;
      lsum *= alpha;
#pragma unroll
      for (int cb = 0; cb < 8; ++cb)
#pragma unroll
        for (int r = 0; r < 16; ++r) o[cb][r] *= alpha;
    }
    float rs = 0.f;
#pragma unroll
    for (int r = 0; r < 16; ++r) { float p = exp2f(s[0][r] - m); s[0][r] = p; rs += p; }
#pragma unroll
    for (int r = 0; r < 16; ++r) { float p = exp2f(s[1][r] - m); s[1][r] = p; rs += p; }
    rs += __shfl_xor(rs, 32);
    lsum += rs;
    // ---- P -> bf16 B-frags via cvt_pk + permlane32_swap (no LDS)
    bf16x8 pb[4];
#pragma unroll
    for (int kb = 0; kb < 2; ++kb) {
      unsigned wv[4], uv[4];
#pragma unroll
      for (int j = 0; j < 4; ++j) {
        asm("v_cvt_pk_bf16_f32 %0, %1, %2"
            : "=v"(wv[j]) : "v"(s[kb][4 * j + 0]), "v"(s[kb][4 * j + 1]));
        asm("v_cvt_pk_bf16_f32 %0, %1, %2"
            : "=v"(uv[j]) : "v"(s[kb][4 * j + 2]), "v"(s[kb][4 * j + 3]));
      }
#pragma unroll
      for (int jj = 0; jj < 2; ++jj) {
        uint2v rw = __builtin_amdgcn_permlane32_swap(wv[2 * jj], wv[2 * jj + 1], false, false);
        uint2v ru = __builtin_amdgcn_permlane32_swap(uv[2 * jj], uv[2 * jj + 1], false, false);
        unsigned tmp[4] = { rw[0], ru[0], rw[1], ru[1] };
        bf16x8 t; __builtin_memcpy(&t, tmp, 16);
        pb[kb * 2 + jj] = t;
      }
    }
    // ---- O^T += V^T x P^T
#pragma unroll
    for (int cb = 0; cb < 8; ++cb) {
      int c = cb * 32 + qcol;
#pragma unroll
      for (int ks = 0; ks < 4; ++ks) {
        int cc = ks * 2 + hi;
        bf16x8 va = *(const bf16x8*)(Vc + c * 128 + ((cc ^ (c & 7)) << 4));
        o[cb] = mfma32(va, pb[ks], o[cb]);
      }
    }
    asm volatile("" ::: "memory");
    __builtin_amdgcn_sched_barrier(0);
    __builtin_amdgcn_s_barrier();   // all waves done reading cur; next stage may overwrite
  }
  // ---- epilogue: transpose per-wave via LDS scratch, coalesced stores
  char* tb = Lds + w * 4096;  // 4 KB/wave; safe after final barrier
  const size_t rb = (size_t)b * NQ + qt * 128 + w * 32;
  if (nsplit == 1) {
    float inv = 1.f / lsum;
#pragma unroll
    for (int cb = 0; cb < 8; ++cb) {
#pragma unroll
      for (int j = 0; j < 4; ++j) {
        f32x4 v;
        v[0] = o[cb][4 * j + 0] * inv; v[1] = o[cb][4 * j + 1] * inv;
        v[2] = o[cb][4 * j + 2] * inv; v[3] = o[cb][4 * j + 3] * inv;
        *(f32x4*)(tb + qcol * 128 + (((2 * j + hi) ^ (qcol & 7)) << 4)) = v;
      }
#pragma unroll
      for (int jr = 0; jr < 4; ++jr) {
        int qr = jr * 8 + (ln >> 3), cc = ln & 7;
        f32x4 v = *(const f32x4*)(tb + qr * 128 + ((cc ^ (qr & 7)) << 4));
        *(f32x4*)(xr + (rb + qr) * CC + cb * 32 + cc * 4) = v;
      }
    }
  } else {
#pragma unroll
    for (int cb = 0; cb < 8; ++cb) {
#pragma unroll
      for (int j = 0; j < 4; ++j) {
        f32x4 v;
        v[0] = o[cb][4 * j + 0]; v[1] = o[cb][4 * j + 1];
        v[2] = o[cb][4 * j + 2]; v[3] = o[cb][4 * j + 3];
        *(f32x4*)(tb + qcol * 128 + (((2 * j + hi) ^ (qcol & 7)) << 4)) = v;
      }
#pragma unroll
      for (int jr = 0; jr < 4; ++jr) {
        int qr = jr * 8 + (ln >> 3), cc = ln & 7;
        f32x4 v = *(const f32x4*)(tb + qr * 128 + ((cc ^ (qr & 7)) << 4));
        S4 sv; sv.x = f2bf(v[0]); sv.y = f2bf(v[1]); sv.z = f2bf(v[2]); sv.w = f2bf(v[3]);
        *(S4*)(po + ((size_t)kz * NROWS + rb + qr) * CC + cb * 32 + cc * 4) = sv;
      }
    }
    if (ln < 32) {
      size_t g = (size_t)kz * NROWS + rb + qcol;
      pm[g] = m;
      pl[g] = lsum;
    }
  }
}

// ---------------- combine 4 k-split partials -> xr (log2 domain) -------------
__global__ __launch_bounds__(256)
void k_combine(const short* __restrict__ po, const float* __restrict__ pm,
               const float* __restrict__ pl, float* __restrict__ xr) {
  int t = blockIdx.x * 256 + threadIdx.x;      // NROWS*64 quads
  int row = t >> 6, cq = (t & 63) * 4;
  float mi[4], li[4];
#pragma unroll
  for (int i = 0; i < 4; ++i) {
    mi[i] = pm[(size_t)i * NROWS + row];
    li[i] = pl[(size_t)i * NROWS + row];
  }
  float M = fmaxf(fmaxf(mi[0], mi[1]), fmaxf(mi[2], mi[3]));
  float wi[4], L = 0.f;
#pragma unroll
  for (int i = 0; i < 4; ++i) { wi[i] = exp2f(mi[i] - M); L += li[i] * wi[i]; }
  float invL = 1.f / L;
  float a0 = 0, a1 = 0, a2 = 0, a3 = 0;
#pragma unroll
  for (int i = 0; i < 4; ++i) {
    S4 v = *(const S4*)(po + ((size_t)i * NROWS + row) * CC + cq);
    a0 += bf2f(v.x) * wi[i]; a1 += bf2f(v.y) * wi[i];
    a2 += bf2f(v.z) * wi[i]; a3 += bf2f(v.w) * wi[i];
  }
  float4 r; r.x = a0 * invL; r.y = a1 * invL; r.z = a2 * invL; r.w = a3 * invL;
  *(float4*)(xr + (size_t)row * CC + cq) = r;
}

// ---------------- epilogue: out = relu(BN((q - xr) wt^T + bt)) + q -----------
// 16 rows/wave, 64 rows/block -> grid (256,2) = 512 blocks
__global__ __launch_bounds__(256)
void k_epilogue(const float* __restrict__ q, const float* __restrict__ xr,
                const short* __restrict__ wtb, const float* __restrict__ scale,
                const float* __restrict__ bias, float* __restrict__ out) {
  const int lane = threadIdx.x & 63, w = threadIdx.x >> 6;
  const int rowbase = blockIdx.x * 64 + w * 16;
  const int cb = blockIdx.y * 128;
  const int lr = lane & 15, lg = lane >> 4;
  f32x4 acc[8] = {};
#pragma unroll
  for (int kf = 0; kf < 8; ++kf) {
    size_t base = (size_t)(rowbase + lr) * CC + kf * 32 + lg * 8;
    float4 q0 = *(const float4*)(q + base), q1 = *(const float4*)(q + base + 4);
    float4 r0 = *(const float4*)(xr + base), r1 = *(const float4*)(xr + base + 4);
    bf16x8 a;
    a[0] = f2bf(q0.x - r0.x); a[1] = f2bf(q0.y - r0.y);
    a[2] = f2bf(q0.z - r0.z); a[3] = f2bf(q0.w - r0.w);
    a[4] = f2bf(q1.x - r1.x); a[5] = f2bf(q1.y - r1.y);
    a[6] = f2bf(q1.z - r1.z); a[7] = f2bf(q1.w - r1.w);
#pragma unroll
    for (int nf = 0; nf < 8; ++nf) {
      bf16x8 b = *(const bf16x8*)(wtb + (size_t)(cb + nf * 16 + lr) * CC + kf * 32 + lg * 8);
      acc[nf] = mfma16(a, b, acc[nf]);
    }
  }
#pragma unroll
  for (int nf = 0; nf < 8; ++nf) {
    int c = cb + nf * 16 + lr;
    float sc = scale[c], bi = bias[c];
#pragma unroll
    for (int r = 0; r < 4; ++r) {
      int row = rowbase + lg * 4 + r;
      float y = acc[nf][r] * sc + bi;
      y = fmaxf(y, 0.f) + q[(size_t)row * CC + c];
      out[(size_t)row * CC + c] = y;
    }
  }
}

// ---------------- launch -----------------------------------------------------
extern "C" void kernel_launch(void* const* d_in, const int* in_sizes, int n_in,
                              void* d_out, int out_size, void* d_ws, size_t ws_size,
                              hipStream_t stream) {
  const float* q     = (const float*)d_in[0];
  const float* kv    = (const float*)d_in[1];
  const float* wq    = (const float*)d_in[2];
  const float* wk    = (const float*)d_in[3];
  const float* wv    = (const float*)d_in[4];
  const float* wt    = (const float*)d_in[5];
  const float* bt    = (const float*)d_in[6];
  const float* gmm   = (const float*)d_in[7];
  const float* bet   = (const float*)d_in[8];
  const float* rmean = (const float*)d_in[9];
  const float* rvar  = (const float*)d_in[10];
  float* out = (float*)d_out;
  char* ws = (char*)d_ws;

  short* wqb  = (short*)(ws + 0);         // 32 KB
  short* wkb  = (short*)(ws + 32768);     // 32 KB
  short* wvb  = (short*)(ws + 65536);     // 128 KB
  short* wtb  = (short*)(ws + 196608);    // 128 KB
  float* scale= (float*)(ws + 327680);    // 1 KB
  float* bias = (float*)(ws + 328704);    // 1 KB
  short* xq   = (short*)(ws + 329728);    // 2 MB
  short* xk   = (short*)(ws + 2426880);   // 2 MB
  short* vt   = (short*)(ws + 4524032);   // 8 MB
  float* xr   = (float*)(ws + 12912640);  // 16 MB
  short* po   = (short*)(ws + 29689856);  // 32 MB (4 x 16384 x 256 bf16)
  float* pm   = (float*)(ws + 63244288);  // 256 KB
  float* pl   = (float*)(ws + 63506432);  // 256 KB
  const size_t NEED = 63768576;
  const int nsplit = (ws_size >= NEED) ? 4 : 1;

  k_setup<<<256, 256, 0, stream>>>(wq, wk, wv, wt, bt, gmm, bet, rmean, rvar,
                                   wqb, wkb, wvb, wtb, scale, bias);
  k_projqk<<<dim3(256, 2), 256, 0, stream>>>(q, kv, wqb, wkb, xq, xk);
  k_projv<<<dim3(256, 2), 256, 0, stream>>>(kv, wvb, vt);
  k_attn<<<dim3(64, 2, nsplit), 256, 0, stream>>>(xq, xk, vt, xr, po, pm, pl, nsplit);
  if (nsplit > 1)
    k_combine<<<NROWS * 64 / 256, 256, 0, stream>>>(po, pm, pl, xr);
  k_epilogue<<<dim3(256, 2), 256, 0, stream>>>(q, xr, wtb, scale, bias, out);
}